// Round 2
// baseline (412.269 us; speedup 1.0000x reference)
//
#include <hip/hip_runtime.h>
#include <math.h>

#define HID   2048
#define NEXP  64
#define NTOK  16384
#define NBLK  256
#define TOLF  1e-4f
#define EPSF  1e-8f

// ---------------------------------------------------------------------------
// Kernel 1: logits partials. Grid = 512 blocks (256 token-tiles x 2 K-halves),
// 256 threads. Tile = 64 tokens x 64 experts, K-half = 1024 (16 chunks of 64).
// P[half][t][e] = sum_{k in half} x[t][k] * W[e][k]
// Both LDS tiles stored k-major so the inner loop is 2x ds_read_b128.
// ---------------------------------------------------------------------------
__global__ __launch_bounds__(256) void gemm_logits(const float* __restrict__ x,
                                                   const float* __restrict__ W,
                                                   float* __restrict__ P) {
    __shared__ float xTs[64][68];   // [k][token], padded (68*4B = 17*16B, keeps 16B align)
    __shared__ float wTs[64][68];   // [k][expert]

    const int bx   = blockIdx.x;
    const int tile = bx & 255;
    const int half = bx >> 8;
    const int tid  = threadIdx.x;
    const int lt   = tid >> 4;         // 0..15 (row group for staging)
    const int lk   = (tid & 15) * 4;   // 0..60 (k offset for staging)
    const int ty   = tid >> 4;         // token group: tokens 4*ty..4*ty+3
    const int tx   = tid & 15;         // expert group: experts 4*tx..4*tx+3

    float acc[4][4];
#pragma unroll
    for (int a = 0; a < 4; ++a)
#pragma unroll
        for (int b = 0; b < 4; ++b) acc[a][b] = 0.0f;

    const float* xb = x + (size_t)(tile * 64) * HID + half * 1024;
    const float* wb = W + half * 1024;
    float*       Pb = P + (size_t)half * NTOK * NEXP + (size_t)(tile * 64) * NEXP;

    for (int c = 0; c < 16; ++c) {
        const int k0 = c * 64;
        // stage x tile transposed: xTs[k][token]
#pragma unroll
        for (int r = 0; r < 4; ++r) {
            const int t = lt + 16 * r;
            float4 v = *(const float4*)(xb + (size_t)t * HID + k0 + lk);
            xTs[lk + 0][t] = v.x;
            xTs[lk + 1][t] = v.y;
            xTs[lk + 2][t] = v.z;
            xTs[lk + 3][t] = v.w;
        }
        // stage W chunk transposed: wTs[k][expert]
#pragma unroll
        for (int r = 0; r < 4; ++r) {
            const int e = lt + 16 * r;
            float4 v = *(const float4*)(wb + (size_t)e * HID + k0 + lk);
            wTs[lk + 0][e] = v.x;
            wTs[lk + 1][e] = v.y;
            wTs[lk + 2][e] = v.z;
            wTs[lk + 3][e] = v.w;
        }
        __syncthreads();

#pragma unroll 8
        for (int k = 0; k < 64; ++k) {
            const float4 a4 = *(const float4*)&xTs[k][ty * 4];
            const float4 b4 = *(const float4*)&wTs[k][tx * 4];
            acc[0][0] = fmaf(a4.x, b4.x, acc[0][0]);
            acc[0][1] = fmaf(a4.x, b4.y, acc[0][1]);
            acc[0][2] = fmaf(a4.x, b4.z, acc[0][2]);
            acc[0][3] = fmaf(a4.x, b4.w, acc[0][3]);
            acc[1][0] = fmaf(a4.y, b4.x, acc[1][0]);
            acc[1][1] = fmaf(a4.y, b4.y, acc[1][1]);
            acc[1][2] = fmaf(a4.y, b4.z, acc[1][2]);
            acc[1][3] = fmaf(a4.y, b4.w, acc[1][3]);
            acc[2][0] = fmaf(a4.z, b4.x, acc[2][0]);
            acc[2][1] = fmaf(a4.z, b4.y, acc[2][1]);
            acc[2][2] = fmaf(a4.z, b4.z, acc[2][2]);
            acc[2][3] = fmaf(a4.z, b4.w, acc[2][3]);
            acc[3][0] = fmaf(a4.w, b4.x, acc[3][0]);
            acc[3][1] = fmaf(a4.w, b4.y, acc[3][1]);
            acc[3][2] = fmaf(a4.w, b4.z, acc[3][2]);
            acc[3][3] = fmaf(a4.w, b4.w, acc[3][3]);
        }
        __syncthreads();
    }

#pragma unroll
    for (int j = 0; j < 4; ++j) {
        float4 v = make_float4(acc[j][0], acc[j][1], acc[j][2], acc[j][3]);
        *(float4*)(Pb + (size_t)(ty * 4 + j) * NEXP + tx * 4) = v;
    }
}

// ---------------------------------------------------------------------------
// Kernel 2: sinkhorn + top-2 + softmax gather. REGULAR launch (no cooperative)
// with a hand-rolled monotonic grid barrier. 256 blocks x 256 threads =
// 1 block/CU (52 VGPR, tiny LDS) -> co-resident, no deadlock.
// Wave w of block b owns tokens b*64 + w*16 .. +15; lane = expert.
// ---------------------------------------------------------------------------
__global__ __launch_bounds__(256) void sinkhorn_router(const float* __restrict__ P,
                                                       float* __restrict__ colbuf,
                                                       int* __restrict__ bar,
                                                       float* __restrict__ out) {
    __shared__ float part[4][64];
    __shared__ float red[4][64];
    __shared__ float d1s[64];
    __shared__ float err_s;

    const int b     = blockIdx.x;   // 0..255
    const int tid   = threadIdx.x;
    const int w     = tid >> 6;     // wave 0..3
    const int lane  = tid & 63;     // expert index
    const int tbase = b * 64 + w * 16;
    const int eq    = tid & 63;     // expert handled in cross-block reduction
    const int qq    = tid >> 6;     // block-quarter handled in reduction

    float logit[16], cost[16], dreg[16];
#pragma unroll
    for (int j = 0; j < 16; ++j) {
        const int t = tbase + j;
        const float l0 = P[(size_t)t * NEXP + lane];
        const float l1 = P[(size_t)NTOK * NEXP + (size_t)t * NEXP + lane];
        const float l  = l0 + l1;
        logit[j] = l;
        cost[j]  = expf(l);
        dreg[j]  = 0.0f;
    }

    float d1l   = 1.0f;   // this lane's d1[e]
    float d1old = 1.0f;   // previous d1 for expert eq (err computation)
    int   g     = 0;

    for (;;) {
        // ---- phase A: d0 per token + per-wave column partials ----
        float colacc = 0.0f;
#pragma unroll
        for (int j = 0; j < 16; ++j) {
            float s = d1l * cost[j];
#pragma unroll
            for (int m = 32; m; m >>= 1) s += __shfl_xor(s, m, 64);
            const float d0 = (1.0f / 16384.0f) / (s + EPSF);
            dreg[j] = d0;
            colacc = fmaf(d0, cost[j], colacc);
        }
        part[w][lane] = colacc;
        __syncthreads();

        float* cb = colbuf + (size_t)(g & 1) * (NEXP * NBLK);
        if (tid < 64) {
            const float s4 = part[0][tid] + part[1][tid] + part[2][tid] + part[3][tid];
            cb[tid * NBLK + b] = s4;
        }
        __threadfence();            // device-scope release: colbuf visible across XCDs
        __syncthreads();

        // ---- grid barrier (monotonic arrive counter) ----
        if (tid == 0) {
            __hip_atomic_fetch_add(bar, 1, __ATOMIC_ACQ_REL, __HIP_MEMORY_SCOPE_AGENT);
            const int target = NBLK * (g + 1);
            while (__hip_atomic_load(bar, __ATOMIC_ACQUIRE, __HIP_MEMORY_SCOPE_AGENT) < target)
                __builtin_amdgcn_s_sleep(1);
        }
        __syncthreads();
        __threadfence();            // device-scope acquire: invalidate stale L1/L2 lines

        // ---- phase B: deterministic cross-block column reduction ----
        const float* ce = cb + eq * NBLK + qq * 64;
        float tot = 0.0f;
#pragma unroll
        for (int q = 0; q < 16; ++q) {
            float4 v = *(const float4*)(ce + q * 4);
            tot += v.x; tot += v.y; tot += v.z; tot += v.w;
        }
        red[qq][eq] = tot;
        __syncthreads();

        if (tid < 64) {
            const float t4  = red[0][tid] + red[1][tid] + red[2][tid] + red[3][tid];
            const float d1n = (1.0f / 64.0f) / (t4 + EPSF);
            float diff = fabsf(d1old - d1n);
#pragma unroll
            for (int m = 32; m; m >>= 1) diff += __shfl_xor(diff, m, 64);
            d1s[tid] = d1n;
            d1old    = d1n;
            if (tid == 0) err_s = diff * (1.0f / 64.0f);
        }
        __syncthreads();
        d1l = d1s[lane];
        const float err = err_s;
        ++g;
        if (!(err > TOLF) || g >= 512) break;
    }

    // ---- final: per token top-2 of d1*cost*d0, softmax gather ----
#pragma unroll 1
    for (int j = 0; j < 16; ++j) {
        const int t = tbase + j;
        const float v = (d1l * cost[j]) * dreg[j];

        float bv = v; int bi = lane;
#pragma unroll
        for (int m = 32; m; m >>= 1) {
            const float ov = __shfl_xor(bv, m, 64);
            const int   oi = __shfl_xor(bi, m, 64);
            if (ov > bv || (ov == bv && oi < bi)) { bv = ov; bi = oi; }
        }
        const int i1 = bi;

        float v2 = (lane == i1) ? -INFINITY : v;
        float bv2 = v2; int bi2 = lane;
#pragma unroll
        for (int m = 32; m; m >>= 1) {
            const float ov = __shfl_xor(bv2, m, 64);
            const int   oi = __shfl_xor(bi2, m, 64);
            if (ov > bv2 || (ov == bv2 && oi < bi2)) { bv2 = ov; bi2 = oi; }
        }
        const int i2 = bi2;

        // softmax over the 64 logits (max-subtracted, matching jax.nn.softmax)
        float mx = logit[j];
#pragma unroll
        for (int m = 32; m; m >>= 1) mx = fmaxf(mx, __shfl_xor(mx, m, 64));
        const float e = expf(logit[j] - mx);
        float se = e;
#pragma unroll
        for (int m = 32; m; m >>= 1) se += __shfl_xor(se, m, 64);

        const float p1 = __shfl(e, i1, 64) / se;
        const float p2 = __shfl(e, i2, 64) / se;

        if (lane == 0) {
            out[(size_t)t * 2 + 0] = p1;
            out[(size_t)t * 2 + 1] = p2;
            out[(size_t)NTOK * 2 + (size_t)t * 2 + 0] = (float)i1;
            out[(size_t)NTOK * 2 + (size_t)t * 2 + 1] = (float)i2;
        }
    }
}

// ---------------------------------------------------------------------------
extern "C" void kernel_launch(void* const* d_in, const int* in_sizes, int n_in,
                              void* d_out, int out_size, void* d_ws, size_t ws_size,
                              hipStream_t stream) {
    const float* x = (const float*)d_in[0];
    const float* W = (const float*)d_in[1];
    float* out = (float*)d_out;

    float* P      = (float*)d_ws;                      // 2 * 16384*64 floats = 8 MB
    float* colbuf = P + (size_t)2 * NTOK * NEXP;       // 2 * 64 * 256 floats = 128 KB
    int*   bar    = (int*)(colbuf + (size_t)2 * NEXP * NBLK);

    // barrier counter must start at 0 every call (d_ws is re-poisoned to 0xAA)
    hipMemsetAsync(bar, 0, 64, stream);

    gemm_logits<<<dim3(512), dim3(256), 0, stream>>>(x, W, P);
    sinkhorn_router<<<dim3(NBLK), dim3(256), 0, stream>>>(P, colbuf, bar, out);
}

// Round 3
// 327.737 us; speedup vs baseline: 1.2579x; 1.2579x over previous
//
#include <hip/hip_runtime.h>
#include <hip/hip_cooperative_groups.h>
#include <math.h>

#define HID   2048
#define NEXP  64
#define NTOK  16384
#define SBLK  64      // sinkhorn blocks
#define TOLF  1e-4f
#define EPSF  1e-8f

// ---------------------------------------------------------------------------
// Kernel 1: logits partials. Grid = 512 blocks (256 token-tiles x 2 K-halves),
// 256 threads. Tile = 64 tokens x 64 experts, K-half = 1024 (16 chunks of 64).
// P[half][t][e] = sum_{k in half} x[t][k] * W[e][k]
// Both LDS tiles stored k-major so the inner loop is 2x ds_read_b128.
// ---------------------------------------------------------------------------
__global__ __launch_bounds__(256) void gemm_logits(const float* __restrict__ x,
                                                   const float* __restrict__ W,
                                                   float* __restrict__ P) {
    __shared__ float xTs[64][68];   // [k][token], padded
    __shared__ float wTs[64][68];   // [k][expert]

    const int bx   = blockIdx.x;
    const int tile = bx & 255;
    const int half = bx >> 8;
    const int tid  = threadIdx.x;
    const int lt   = tid >> 4;         // 0..15 (row group for staging)
    const int lk   = (tid & 15) * 4;   // 0..60 (k offset for staging)
    const int ty   = tid >> 4;         // token group: tokens 4*ty..4*ty+3
    const int tx   = tid & 15;         // expert group: experts 4*tx..4*tx+3

    float acc[4][4];
#pragma unroll
    for (int a = 0; a < 4; ++a)
#pragma unroll
        for (int b = 0; b < 4; ++b) acc[a][b] = 0.0f;

    const float* xb = x + (size_t)(tile * 64) * HID + half * 1024;
    const float* wb = W + half * 1024;
    float*       Pb = P + (size_t)half * NTOK * NEXP + (size_t)(tile * 64) * NEXP;

    for (int c = 0; c < 16; ++c) {
        const int k0 = c * 64;
#pragma unroll
        for (int r = 0; r < 4; ++r) {
            const int t = lt + 16 * r;
            float4 v = *(const float4*)(xb + (size_t)t * HID + k0 + lk);
            xTs[lk + 0][t] = v.x;
            xTs[lk + 1][t] = v.y;
            xTs[lk + 2][t] = v.z;
            xTs[lk + 3][t] = v.w;
        }
#pragma unroll
        for (int r = 0; r < 4; ++r) {
            const int e = lt + 16 * r;
            float4 v = *(const float4*)(wb + (size_t)e * HID + k0 + lk);
            wTs[lk + 0][e] = v.x;
            wTs[lk + 1][e] = v.y;
            wTs[lk + 2][e] = v.z;
            wTs[lk + 3][e] = v.w;
        }
        __syncthreads();

#pragma unroll 8
        for (int k = 0; k < 64; ++k) {
            const float4 a4 = *(const float4*)&xTs[k][ty * 4];
            const float4 b4 = *(const float4*)&wTs[k][tx * 4];
            acc[0][0] = fmaf(a4.x, b4.x, acc[0][0]);
            acc[0][1] = fmaf(a4.x, b4.y, acc[0][1]);
            acc[0][2] = fmaf(a4.x, b4.z, acc[0][2]);
            acc[0][3] = fmaf(a4.x, b4.w, acc[0][3]);
            acc[1][0] = fmaf(a4.y, b4.x, acc[1][0]);
            acc[1][1] = fmaf(a4.y, b4.y, acc[1][1]);
            acc[1][2] = fmaf(a4.y, b4.z, acc[1][2]);
            acc[1][3] = fmaf(a4.y, b4.w, acc[1][3]);
            acc[2][0] = fmaf(a4.z, b4.x, acc[2][0]);
            acc[2][1] = fmaf(a4.z, b4.y, acc[2][1]);
            acc[2][2] = fmaf(a4.z, b4.z, acc[2][2]);
            acc[2][3] = fmaf(a4.z, b4.w, acc[2][3]);
            acc[3][0] = fmaf(a4.w, b4.x, acc[3][0]);
            acc[3][1] = fmaf(a4.w, b4.y, acc[3][1]);
            acc[3][2] = fmaf(a4.w, b4.z, acc[3][2]);
            acc[3][3] = fmaf(a4.w, b4.w, acc[3][3]);
        }
        __syncthreads();
    }

#pragma unroll
    for (int j = 0; j < 4; ++j) {
        float4 v = make_float4(acc[j][0], acc[j][1], acc[j][2], acc[j][3]);
        *(float4*)(Pb + (size_t)(ty * 4 + j) * NEXP + tx * 4) = v;
    }
}

// ---------------------------------------------------------------------------
// Kernel 2 (cooperative): sinkhorn + top-2 + softmax gather.
// Grid = 64 blocks x 1024 threads (narrow barrier: arrivals serialize on one
// line, ~17ns each -> 64 arrivals ~1.1us vs 256 ~4.4us). Wave w (0..15) of
// block b owns tokens b*256 + w*16 .. +15; lane = expert. cost in registers.
// ---------------------------------------------------------------------------
__global__ __launch_bounds__(1024) void sinkhorn_router(const float* __restrict__ P,
                                                        float* __restrict__ colbuf,
                                                        float* __restrict__ out) {
    cooperative_groups::grid_group grid = cooperative_groups::this_grid();

    __shared__ float part[16][64];
    __shared__ float redq[64][17];
    __shared__ float d1s[64];
    __shared__ float err_s;

    const int b     = blockIdx.x;   // 0..63
    const int tid   = threadIdx.x;
    const int w     = tid >> 6;     // wave 0..15
    const int lane  = tid & 63;     // expert index
    const int tbase = b * 256 + w * 16;

    float logit[16], cost[16], dreg[16];
#pragma unroll
    for (int j = 0; j < 16; ++j) {
        const int t = tbase + j;
        const float l0 = P[(size_t)t * NEXP + lane];
        const float l1 = P[(size_t)NTOK * NEXP + (size_t)t * NEXP + lane];
        const float l  = l0 + l1;
        logit[j] = l;
        cost[j]  = expf(l);
        dreg[j]  = 0.0f;
    }

    float d1l   = 1.0f;   // this lane's d1[e]
    float d1old = 1.0f;   // previous d1 (used by tid<64 for err)
    int   g     = 0;

    for (;;) {
        // ---- phase A: d0 per token + per-wave column partials ----
        float colacc = 0.0f;
#pragma unroll
        for (int j = 0; j < 16; ++j) {
            float s = d1l * cost[j];
#pragma unroll
            for (int m = 32; m; m >>= 1) s += __shfl_xor(s, m, 64);
            const float d0 = (1.0f / 16384.0f) / (s + EPSF);
            dreg[j] = d0;
            colacc = fmaf(d0, cost[j], colacc);
        }
        part[w][lane] = colacc;
        __syncthreads();

        float* cb = colbuf + (size_t)(g & 1) * (NEXP * SBLK);
        if (tid < 64) {
            float s = part[0][tid];
#pragma unroll
            for (int q = 1; q < 16; ++q) s += part[q][tid];
            cb[tid * SBLK + b] = s;     // reader-coalesced layout [e][b]
        }
        grid.sync();

        // ---- phase B: cross-block column reduction, all 1024 threads ----
        {
            const int e = tid >> 4;     // 0..63
            const int q = tid & 15;     // 0..15 -> blocks q*4..q*4+3
            float4 v = *(const float4*)(cb + e * SBLK + q * 4);
            redq[e][q] = (v.x + v.y) + (v.z + v.w);
        }
        __syncthreads();

        if (tid < 64) {
            float tot = redq[tid][0];
#pragma unroll
            for (int q = 1; q < 16; ++q) tot += redq[tid][q];
            const float d1n = (1.0f / 64.0f) / (tot + EPSF);
            float diff = fabsf(d1old - d1n);
#pragma unroll
            for (int m = 32; m; m >>= 1) diff += __shfl_xor(diff, m, 64);
            d1s[tid] = d1n;
            d1old    = d1n;
            if (tid == 0) err_s = diff * (1.0f / 64.0f);
        }
        __syncthreads();
        d1l = d1s[lane];
        const float err = err_s;
        ++g;
        if (!(err > TOLF) || g >= 512) break;   // matches while(err>tol); NaN stops
    }

    // ---- final: per token top-2 of d1*cost*d0, softmax gather ----
#pragma unroll 1
    for (int j = 0; j < 16; ++j) {
        const int t = tbase + j;
        const float v = (d1l * cost[j]) * dreg[j];

        float bv = v; int bi = lane;
#pragma unroll
        for (int m = 32; m; m >>= 1) {
            const float ov = __shfl_xor(bv, m, 64);
            const int   oi = __shfl_xor(bi, m, 64);
            if (ov > bv || (ov == bv && oi < bi)) { bv = ov; bi = oi; }
        }
        const int i1 = bi;

        float v2 = (lane == i1) ? -INFINITY : v;
        float bv2 = v2; int bi2 = lane;
#pragma unroll
        for (int m = 32; m; m >>= 1) {
            const float ov = __shfl_xor(bv2, m, 64);
            const int   oi = __shfl_xor(bi2, m, 64);
            if (ov > bv2 || (ov == bv2 && oi < bi2)) { bv2 = ov; bi2 = oi; }
        }
        const int i2 = bi2;

        float mx = logit[j];
#pragma unroll
        for (int m = 32; m; m >>= 1) mx = fmaxf(mx, __shfl_xor(mx, m, 64));
        const float e = expf(logit[j] - mx);
        float se = e;
#pragma unroll
        for (int m = 32; m; m >>= 1) se += __shfl_xor(se, m, 64);

        const float p1 = __shfl(e, i1, 64) / se;
        const float p2 = __shfl(e, i2, 64) / se;

        if (lane == 0) {
            out[(size_t)t * 2 + 0] = p1;
            out[(size_t)t * 2 + 1] = p2;
            out[(size_t)NTOK * 2 + (size_t)t * 2 + 0] = (float)i1;
            out[(size_t)NTOK * 2 + (size_t)t * 2 + 1] = (float)i2;
        }
    }
}

// ---------------------------------------------------------------------------
extern "C" void kernel_launch(void* const* d_in, const int* in_sizes, int n_in,
                              void* d_out, int out_size, void* d_ws, size_t ws_size,
                              hipStream_t stream) {
    const float* x = (const float*)d_in[0];
    const float* W = (const float*)d_in[1];
    float* out = (float*)d_out;

    float* P      = (float*)d_ws;                      // 2 * 16384*64 floats = 8 MB
    float* colbuf = P + (size_t)2 * NTOK * NEXP;       // 2 * 64*64 floats = 32 KB

    gemm_logits<<<dim3(512), dim3(256), 0, stream>>>(x, W, P);

    void* args[] = { (void*)&P, (void*)&colbuf, (void*)&out };
    hipLaunchCooperativeKernel((void*)sinkhorn_router, dim3(SBLK), dim3(1024),
                               args, 0, stream);
}